// Round 1
// baseline (160.297 us; speedup 1.0000x reference)
//
#include <hip/hip_runtime.h>

// LocallyConnected1d: out[b,o,i] = sum_{c,k} x[b,c,i+k] * w[o,c,i,k] + C_IN*bias[o,i]
// B=128, C_IN=64, C_OUT=64, L=1024, K=9, L_OUT=1016
//
// Strategy: per-position GEMM (M=128 batch, N=64 c_out, K=576=c*k) with bf16 MFMA.
// One block per position i; weights (150 MB, the dominant HBM stream) read exactly once.
// XCD-chunked swizzle (1016 = 8*127) keeps i-neighbors on the same XCD L2 so
// 36-B weight runs and stride-4064B output stores merge in L2.

#define NB   128   // batch (GEMM M)
#define CIN  64
#define COUT 64    // GEMM N
#define LIN  1024
#define KW   9
#define LOUT 1016
#define KTOT 576   // CIN*KW (GEMM K)
#define KC   32    // K-chunk (one 16x16x32 MFMA deep)
#define NCH  18    // KTOT/KC
#define PAD  40    // LDS row stride in halfwords (32 + 8 pad -> 2-way bank alias = free)

typedef __attribute__((ext_vector_type(4))) float f32x4;
typedef __attribute__((ext_vector_type(8))) short bf16x8;

static __device__ __forceinline__ unsigned short f2bf(float f) {
    unsigned int u = __float_as_uint(f);
    u += 0x7fffu + ((u >> 16) & 1u);   // round-to-nearest-even
    return (unsigned short)(u >> 16);
}

__global__ __launch_bounds__(512, 4) void lc1d_mfma(
    const float* __restrict__ x, const float* __restrict__ w,
    const float* __restrict__ bias, float* __restrict__ out)
{
    // bijective XCD swizzle: 1016 = 8 * 127 exactly
    const int i    = ((int)(blockIdx.x & 7)) * 127 + ((int)blockIdx.x >> 3);
    const int tid  = threadIdx.x;
    const int lane = tid & 63;
    const int wid  = tid >> 6;   // 0..7
    const int wm   = wid >> 1;   // 0..3 : M-tile (32 rows)
    const int wn   = wid & 1;    // 0..1 : N-tile (32 cols)
    const int l16  = lane & 15;
    const int l4   = lane >> 4;  // 0..3

    __shared__ unsigned short Alds[NB][PAD];    // x patches  [b][qq]
    __shared__ unsigned short Blds[COUT][PAD];  // weights    [o][qq]

    f32x4 acc[2][2];
    #pragma unroll
    for (int a = 0; a < 2; ++a)
        #pragma unroll
        for (int b = 0; b < 2; ++b)
            acc[a][b] = (f32x4){0.f, 0.f, 0.f, 0.f};

    for (int t = 0; t < NCH; ++t) {
        const int q0 = t * KC;

        // stage weights: 64 o x 32 qq = 2048 elems, 4 per thread
        #pragma unroll
        for (int j = 0; j < 4; ++j) {
            int e  = tid + j * 512;
            int o  = e >> 5, qq = e & 31;
            int q  = q0 + qq;
            int c  = q / 9, k = q - 9 * c;
            float v = w[((o * CIN + c) * LOUT + i) * KW + k];
            Blds[o][qq] = f2bf(v);
        }
        // stage x patches: 128 b x 32 qq = 4096 elems, 8 per thread
        #pragma unroll
        for (int j = 0; j < 8; ++j) {
            int e  = tid + j * 512;
            int b  = e >> 5, qq = e & 31;
            int q  = q0 + qq;
            int c  = q / 9, k = q - 9 * c;
            float v = x[(b * CIN + c) * LIN + i + k];
            Alds[b][qq] = f2bf(v);
        }
        __syncthreads();

        bf16x8 af[2], bfr[2];
        #pragma unroll
        for (int mf = 0; mf < 2; ++mf)
            af[mf] = *reinterpret_cast<const bf16x8*>(&Alds[wm * 32 + mf * 16 + l16][l4 * 8]);
        #pragma unroll
        for (int nf = 0; nf < 2; ++nf)
            bfr[nf] = *reinterpret_cast<const bf16x8*>(&Blds[wn * 32 + nf * 16 + l16][l4 * 8]);

        #pragma unroll
        for (int mf = 0; mf < 2; ++mf)
            #pragma unroll
            for (int nf = 0; nf < 2; ++nf)
                acc[mf][nf] = __builtin_amdgcn_mfma_f32_16x16x32_bf16(
                    af[mf], bfr[nf], acc[mf][nf], 0, 0, 0);

        __syncthreads();
    }

    // epilogue: out[b,o,i] = acc + CIN * bias[o,i]
    // C/D layout (m89): col = lane&15 (=o within 16x16), row = (lane>>4)*4 + reg (=b)
    #pragma unroll
    for (int nf = 0; nf < 2; ++nf) {
        int o = wn * 32 + nf * 16 + l16;
        float bv = 64.0f * bias[o * LOUT + i];
        #pragma unroll
        for (int mf = 0; mf < 2; ++mf) {
            #pragma unroll
            for (int j = 0; j < 4; ++j) {
                int b = wm * 32 + mf * 16 + l4 * 4 + j;
                out[(b * COUT + o) * LOUT + i] = acc[mf][nf][j] + bv;
            }
        }
    }
}

extern "C" void kernel_launch(void* const* d_in, const int* in_sizes, int n_in,
                              void* d_out, int out_size, void* d_ws, size_t ws_size,
                              hipStream_t stream) {
    const float* x    = (const float*)d_in[0];
    const float* w    = (const float*)d_in[1];
    const float* bias = (const float*)d_in[2];
    float* out        = (float*)d_out;
    lc1d_mfma<<<dim3(LOUT), dim3(512), 0, stream>>>(x, w, bias, out);
}

// Round 2
// 157.355 us; speedup vs baseline: 1.0187x; 1.0187x over previous
//
#include <hip/hip_runtime.h>

// LocallyConnected1d: out[b,o,i] = sum_{c,k} x[b,c,i+k] * w[o,c,i,k] + C_IN*bias[o,i]
// B=128, C_IN=64, C_OUT=64, L=1024, K=9, L_OUT=1016
//
// R2 pipeline: coalesce EVERYTHING (R1 was latency-bound on scattered 36-B runs:
// 441 GB/s, 8% VALU, 1.6% MFMA).
//   K1: x[b][c][l] f32 -> xt[l][b*64+c] bf16           (16.8 MB)
//   K2: w[o][c][i][k] f32 -> w2[i][o][k*64+c] bf16     (74.9 MB)  K-order q'=k*64+c
//   K3: per-position GEMM (M=128,N=64,K=576), 9 chunks of K=64 (chunk = one k, all c):
//       A-slab = one contiguous 16 KB row of xt; B-slab = contiguous runs of w2.

#define NB   128
#define CIN  64
#define COUT 64
#define LIN  1024
#define KW   9
#define LOUT 1016

typedef __attribute__((ext_vector_type(4))) float f32x4;
typedef __attribute__((ext_vector_type(8))) short bf16x8;

static __device__ __forceinline__ unsigned short f2bf(float f) {
    unsigned int u = __float_as_uint(f);
    u += 0x7fffu + ((u >> 16) & 1u);   // round-to-nearest-even
    return (unsigned short)(u >> 16);
}

// ---------------- K1: x[b][c][l] f32 -> xt[l][b*64+c] bf16 ----------------
// 512 blocks = 32 b-tiles(4) x 16 l-tiles(64). LDS tile holds c-pairs packed in u32.
__global__ __launch_bounds__(512) void k1_xt(const float* __restrict__ x,
                                             unsigned short* __restrict__ xt)
{
    __shared__ unsigned int T3[64][36];   // [l'][c-pair] (+pad)
    const int t  = threadIdx.x;
    const int b0 = ((int)blockIdx.x >> 4) * 4;
    const int l0 = ((int)blockIdx.x & 15) * 64;
    const int cp = t >> 4;      // 0..31 c-pair
    const int lq = t & 15;      // 0..15 l-quad

    for (int bb = 0; bb < 4; ++bb) {
        const int b = b0 + bb;
        const f32x4* x4 = (const f32x4*)x;
        f32x4 fa = x4[(size_t)(b * 64 + 2 * cp) * 256 + (l0 >> 2) + lq];
        f32x4 fb = x4[(size_t)(b * 64 + 2 * cp + 1) * 256 + (l0 >> 2) + lq];
        #pragma unroll
        for (int m = 0; m < 4; ++m) {
            unsigned int pk = (unsigned int)f2bf(fa[m]) | ((unsigned int)f2bf(fb[m]) << 16);
            T3[lq * 4 + m][cp] = pk;
        }
        __syncthreads();
        {
            const int lp = t >> 3;   // 0..63
            const int fq = t & 7;    // 0..7 : 8 bf16 (4 u32) each
            uint4 v = *(const uint4*)&T3[lp][fq * 4];
            *(uint4*)&xt[(size_t)(l0 + lp) * 8192 + b * 64 + fq * 8] = v;
        }
        __syncthreads();
    }
}

// ---------------- K2: w[o][c][i][k] f32 -> w2[((i*64+o)*576) + k*64+c] bf16 ----------------
// 2048 blocks = 64 o x 32 i-tiles(32; last=24). Reads: contiguous f4 runs per (o,c).
__global__ __launch_bounds__(512) void k2_w2(const float* __restrict__ w,
                                             unsigned short* __restrict__ w2)
{
    __shared__ unsigned short T2[32][584];   // [i'][q'=k*64+c] (+pad)
    const int t  = threadIdx.x;
    const int o  = (int)blockIdx.x & 63;
    const int it = (int)blockIdx.x >> 6;
    const int i0 = it * 32;
    const int n_i = (LOUT - i0) < 32 ? (LOUT - i0) : 32;   // 32 or 24
    const int f4cnt = (n_i * 9) >> 2;                      // 72 or 54 (exact)
    const int c = t >> 3;   // 0..63
    const int g = t & 7;    // 0..7
    const f32x4* w4 = (const f32x4*)w;
    const size_t cbase = (size_t)(o * 64 + c) * 2286 + (size_t)it * 72;  // f4 units

    for (int f4i = g; f4i < f4cnt; f4i += 8) {
        f32x4 v = w4[cbase + f4i];
        #pragma unroll
        for (int m = 0; m < 4; ++m) {
            int e  = f4i * 4 + m;             // < 288
            int ii = (e * 7282) >> 16;        // e/9 (valid for e < ~9000)
            int k  = e - ii * 9;
            T2[ii][k * 64 + c] = f2bf(v[m]);
        }
    }
    __syncthreads();
    const int flat = n_i * 72;                 // rows * (576/8)
    for (int idx = t; idx < flat; idx += 512) {
        int ii = (int)(((unsigned)idx * 58255u) >> 22);   // idx/72 (valid idx<4608)
        int qo = idx - ii * 72;
        uint4 v = *(const uint4*)&T2[ii][qo * 8];
        *(uint4*)&w2[((size_t)(i0 + ii) * 64 + o) * 576 + qo * 8] = v;
    }
}

// ---------------- K3: per-position GEMM from xt + w2 ----------------
__global__ __launch_bounds__(512, 8) void k3_gemm(const unsigned short* __restrict__ xt,
                                                  const unsigned short* __restrict__ w2,
                                                  const float* __restrict__ bias,
                                                  float* __restrict__ out)
{
    __shared__ unsigned short A[128][72];    // stride 144 B: 16B-aligned rows, 2-way banks
    __shared__ unsigned short Bs[64][72];
    const int i    = ((int)(blockIdx.x & 7)) * 127 + ((int)blockIdx.x >> 3);  // bijective XCD swizzle
    const int t    = threadIdx.x;
    const int lane = t & 63;
    const int wid  = t >> 6;
    const int wm   = wid >> 1, wn = wid & 1;
    const int l16  = lane & 15, l4 = lane >> 4;

    f32x4 acc[2][2];
    #pragma unroll
    for (int a = 0; a < 2; ++a)
        #pragma unroll
        for (int b = 0; b < 2; ++b)
            acc[a][b] = (f32x4){0.f, 0.f, 0.f, 0.f};

    const int ab = t >> 2, aq = (t & 3) * 16;   // A staging: row b, u16 col
    const int bo = t >> 3, bq = (t & 7) * 8;    // B staging

    for (int kk = 0; kk < 9; ++kk) {
        const unsigned short* arow = &xt[(size_t)(i + kk) * 8192];
        uint4 va0 = *(const uint4*)&arow[ab * 64 + aq];
        uint4 va1 = *(const uint4*)&arow[ab * 64 + aq + 8];
        uint4 vb  = *(const uint4*)&w2[((size_t)i * 64 + bo) * 576 + kk * 64 + bq];
        *(uint4*)&A[ab][aq]      = va0;
        *(uint4*)&A[ab][aq + 8]  = va1;
        *(uint4*)&Bs[bo][bq]     = vb;
        __syncthreads();
        #pragma unroll
        for (int ks = 0; ks < 2; ++ks) {
            bf16x8 af[2], bf[2];
            #pragma unroll
            for (int mf = 0; mf < 2; ++mf)
                af[mf] = *(const bf16x8*)&A[wm * 32 + mf * 16 + l16][ks * 32 + l4 * 8];
            #pragma unroll
            for (int nf = 0; nf < 2; ++nf)
                bf[nf] = *(const bf16x8*)&Bs[wn * 32 + nf * 16 + l16][ks * 32 + l4 * 8];
            #pragma unroll
            for (int mf = 0; mf < 2; ++mf)
                #pragma unroll
                for (int nf = 0; nf < 2; ++nf)
                    acc[mf][nf] = __builtin_amdgcn_mfma_f32_16x16x32_bf16(
                        af[mf], bf[nf], acc[mf][nf], 0, 0, 0);
        }
        __syncthreads();
    }

    // epilogue: C/D layout (m89): col=lane&15 (=o), row=(lane>>4)*4+reg (=b)
    #pragma unroll
    for (int nf = 0; nf < 2; ++nf) {
        int o = wn * 32 + nf * 16 + l16;
        float bv = 64.0f * bias[o * LOUT + i];
        #pragma unroll
        for (int mf = 0; mf < 2; ++mf)
            #pragma unroll
            for (int j = 0; j < 4; ++j) {
                int b = wm * 32 + mf * 16 + l4 * 4 + j;
                out[((size_t)b * 64 + o) * LOUT + i] = acc[mf][nf][j] + bv;
            }
    }
}

// ---------------- R1 fallback (if ws too small): direct scattered-read GEMM ----------------
__global__ __launch_bounds__(512, 4) void lc1d_legacy(
    const float* __restrict__ x, const float* __restrict__ w,
    const float* __restrict__ bias, float* __restrict__ out)
{
    const int i    = ((int)(blockIdx.x & 7)) * 127 + ((int)blockIdx.x >> 3);
    const int tid  = threadIdx.x;
    const int lane = tid & 63;
    const int wid  = tid >> 6;
    const int wm   = wid >> 1;
    const int wn   = wid & 1;
    const int l16  = lane & 15;
    const int l4   = lane >> 4;

    __shared__ unsigned short Alds[128][40];
    __shared__ unsigned short Blds[64][40];

    f32x4 acc[2][2];
    #pragma unroll
    for (int a = 0; a < 2; ++a)
        #pragma unroll
        for (int b = 0; b < 2; ++b)
            acc[a][b] = (f32x4){0.f, 0.f, 0.f, 0.f};

    for (int tch = 0; tch < 18; ++tch) {
        const int q0 = tch * 32;
        #pragma unroll
        for (int j = 0; j < 4; ++j) {
            int e = tid + j * 512;
            int o = e >> 5, qq = e & 31;
            int q = q0 + qq;
            int c = q / 9, k = q - 9 * c;
            Blds[o][qq] = f2bf(w[((size_t)(o * CIN + c) * LOUT + i) * KW + k]);
        }
        #pragma unroll
        for (int j = 0; j < 8; ++j) {
            int e = tid + j * 512;
            int b = e >> 5, qq = e & 31;
            int q = q0 + qq;
            int c = q / 9, k = q - 9 * c;
            Alds[b][qq] = f2bf(x[(size_t)(b * CIN + c) * LIN + i + k]);
        }
        __syncthreads();
        bf16x8 af[2], bfr[2];
        #pragma unroll
        for (int mf = 0; mf < 2; ++mf)
            af[mf] = *reinterpret_cast<const bf16x8*>(&Alds[wm * 32 + mf * 16 + l16][l4 * 8]);
        #pragma unroll
        for (int nf = 0; nf < 2; ++nf)
            bfr[nf] = *reinterpret_cast<const bf16x8*>(&Blds[wn * 32 + nf * 16 + l16][l4 * 8]);
        #pragma unroll
        for (int mf = 0; mf < 2; ++mf)
            #pragma unroll
            for (int nf = 0; nf < 2; ++nf)
                acc[mf][nf] = __builtin_amdgcn_mfma_f32_16x16x32_bf16(af[mf], bfr[nf], acc[mf][nf], 0, 0, 0);
        __syncthreads();
    }
    #pragma unroll
    for (int nf = 0; nf < 2; ++nf) {
        int o = wn * 32 + nf * 16 + l16;
        float bv = 64.0f * bias[o * LOUT + i];
        #pragma unroll
        for (int mf = 0; mf < 2; ++mf)
            #pragma unroll
            for (int j = 0; j < 4; ++j) {
                int b = wm * 32 + mf * 16 + l4 * 4 + j;
                out[((size_t)b * 64 + o) * LOUT + i] = acc[mf][nf][j] + bv;
            }
    }
}

extern "C" void kernel_launch(void* const* d_in, const int* in_sizes, int n_in,
                              void* d_out, int out_size, void* d_ws, size_t ws_size,
                              hipStream_t stream) {
    const float* x    = (const float*)d_in[0];
    const float* w    = (const float*)d_in[1];
    const float* bias = (const float*)d_in[2];
    float* out        = (float*)d_out;

    const size_t W2B = (size_t)LOUT * 64 * 576 * 2;      // 74,907,648
    const size_t XTB = (size_t)1024 * 128 * 64 * 2;      // 16,777,216

    if (ws_size < W2B + XTB) {
        lc1d_legacy<<<dim3(LOUT), dim3(512), 0, stream>>>(x, w, bias, out);
        return;
    }
    unsigned short* w2 = (unsigned short*)d_ws;
    unsigned short* xt = (unsigned short*)((char*)d_ws + W2B);

    k1_xt  <<<dim3(512),  dim3(512), 0, stream>>>(x, xt);
    k2_w2  <<<dim3(2048), dim3(512), 0, stream>>>(w, w2);
    k3_gemm<<<dim3(LOUT), dim3(512), 0, stream>>>(xt, w2, bias, out);
}